// Round 1
// baseline (2430.120 us; speedup 1.0000x reference)
//
#include <hip/hip_runtime.h>

#define LTOK 4096
#define DHID 2048
#define HKN  16
#define HVN  32
#define DKK  128
#define NTOT 12288

typedef unsigned short u16;
typedef __attribute__((ext_vector_type(8))) short short8;
typedef __attribute__((ext_vector_type(8))) unsigned short u16x8;
typedef __attribute__((ext_vector_type(4))) float f32x4;

__device__ __forceinline__ float b2f(u16 u) {
  unsigned int x = ((unsigned int)u) << 16;
  return __builtin_bit_cast(float, x);
}
__device__ __forceinline__ u16 f2bf(float f) {
  unsigned int u = __builtin_bit_cast(unsigned int, f);
  u += 0x7FFFu + ((u >> 16) & 1u);
  return (u16)(u >> 16);
}

template<int C> __device__ __forceinline__ float dppmv(float x) {
  int i = __builtin_amdgcn_update_dpp(0, __builtin_bit_cast(int, x), C, 0xF, 0xF, true);
  return __builtin_bit_cast(float, i);
}
// all 16 lanes of each 16-lane group end with the group sum (4 VALU-latency ops)
__device__ __forceinline__ float red16(float x) {
  x += dppmv<0xB1>(x);   // quad_perm [1,0,3,2]
  x += dppmv<0x4E>(x);   // quad_perm [2,3,0,1]
  x += dppmv<0x124>(x);  // row_ror:4
  x += dppmv<0x128>(x);  // row_ror:8
  return x;
}

__device__ __forceinline__ void gld16(const void* g, void* l) {
  __builtin_amdgcn_global_load_lds((const __attribute__((address_space(1))) void*)g,
                                   (__attribute__((address_space(3))) void*)l, 16, 0, 0);
}

__device__ __forceinline__ void cstore(u16* C, size_t i, float v) { C[i] = f2bf(v); }
__device__ __forceinline__ void cstore(float* C, size_t i, float v) { C[i] = v; }

// ---------------- fp32 -> bf16 convert ----------------
__global__ __launch_bounds__(256)
void k_cvt(const float* __restrict__ s, u16* __restrict__ d, int n) {
  const int i = (blockIdx.x * 256 + threadIdx.x) * 4;
  const float4 v = *(const float4*)(s + i);
  ushort4 o;
  o.x = f2bf(v.x); o.y = f2bf(v.y); o.z = f2bf(v.z); o.w = f2bf(v.w);
  *(ushort4*)(d + i) = o;
}

// ---------------- fp32 [R][C] -> bf16 [C][R] transpose ----------------
__global__ __launch_bounds__(256)
void k_tr(const float* __restrict__ src, u16* __restrict__ dst, int R, int C) {
  __shared__ float tl[32][33];
  const int r0 = blockIdx.y * 32, c0 = blockIdx.x * 32;
  const int tr = threadIdx.x >> 3, tc = (threadIdx.x & 7) * 4;
  const float4 v = *(const float4*)(src + (size_t)(r0 + tr) * C + c0 + tc);
  tl[tr][tc] = v.x; tl[tr][tc + 1] = v.y; tl[tr][tc + 2] = v.z; tl[tr][tc + 3] = v.w;
  __syncthreads();
  ushort4 o;
  o.x = f2bf(tl[tc + 0][tr]); o.y = f2bf(tl[tc + 1][tr]);
  o.z = f2bf(tl[tc + 2][tr]); o.w = f2bf(tl[tc + 3][tr]);
  *(ushort4*)(dst + (size_t)(c0 + tr) * R + r0 + tc) = o;
}

// ---------------- bf16 MFMA GEMM: C[M][N] = A[M][K] * Bt[N][K]^T ----------------
template<typename OutT>
__global__ __launch_bounds__(256, 2)
void k_gemm(const u16* __restrict__ A, const u16* __restrict__ Bt, OutT* __restrict__ C,
            int M, int N, int K) {
  __shared__ u16 lA[128 * 32];
  __shared__ u16 lB[128 * 32];
  const int tid = threadIdx.x;
  const int lane = tid & 63, wid = tid >> 6;
  const int nt = blockIdx.x, mt = blockIdx.y;
  const int wm = (wid >> 1) * 64, wn = (wid & 1) * 64;
  const size_t sK = (size_t)K;
  const u16* aS = A + (size_t)(mt * 128 + wid * 32 + (lane >> 2)) * sK + (lane & 3) * 8;
  const u16* bS = Bt + (size_t)(nt * 128 + wid * 32 + (lane >> 2)) * sK + (lane & 3) * 8;
  u16* lAw = lA + wid * 1024;  // wave-uniform LDS dest (1KB segs)
  u16* lBw = lB + wid * 1024;
  f32x4 acc[4][4] = {};
  const int aoff = (lane & 15) * 32 + (lane >> 4) * 8;

  for (int k0 = 0; k0 < K; k0 += 32) {
    gld16(aS + k0, lAw);
    gld16(aS + k0 + 16 * sK, lAw + 512);
    gld16(bS + k0, lBw);
    gld16(bS + k0 + 16 * sK, lBw + 512);
    __syncthreads();  // drains vmcnt -> LDS tile ready
    short8 af[4], bfv[4];
#pragma unroll
    for (int i = 0; i < 4; ++i) {
      af[i]  = *(const short8*)&lA[(wm + i * 16) * 32 + aoff];
      bfv[i] = *(const short8*)&lB[(wn + i * 16) * 32 + aoff];
    }
#pragma unroll
    for (int i = 0; i < 4; ++i)
#pragma unroll
      for (int j = 0; j < 4; ++j)
        acc[i][j] = __builtin_amdgcn_mfma_f32_16x16x32_bf16(af[i], bfv[j], acc[i][j], 0, 0, 0);
    __syncthreads();
  }
  const int r0 = mt * 128 + wm + (lane >> 4) * 4;
  const int c0 = nt * 128 + wn + (lane & 15);
#pragma unroll
  for (int i = 0; i < 4; ++i)
#pragma unroll
    for (int j = 0; j < 4; ++j)
#pragma unroll
      for (int e = 0; e < 4; ++e)
        cstore(C, (size_t)(r0 + i * 16 + e) * N + c0 + j * 16, acc[i][j][e]);
}

// ---------------- beta / decay: [L,2048]@[2048,32] x2 + activations ----------------
__global__ __launch_bounds__(256)
void k_ba(const float* __restrict__ h, const float* __restrict__ Wb, const float* __restrict__ Wa,
          const float* __restrict__ A_log, const float* __restrict__ dtb,
          float* __restrict__ beta, float* __restrict__ decay) {
  const int w = threadIdx.x >> 6, lane = threadIdx.x & 63;
  const int t = blockIdx.x * 4 + w;
  const int j = lane & 31;
  const bool isB = lane < 32;
  const float* __restrict__ hr = h + (size_t)t * DHID;
  const float* Wc = isB ? Wb : Wa;
  float acc = 0.f;
  for (int kk = 0; kk < DHID; ++kk) acc = fmaf(hr[kk], Wc[(size_t)kk * HVN + j], acc);
  if (isB) {
    beta[(size_t)t * HVN + j] = 1.f / (1.f + expf(-acc));
  } else {
    float xx = acc + dtb[j];
    float sp = (xx > 20.f) ? xx : log1pf(expf(xx));
    decay[(size_t)t * HVN + j] = expf(-expf(A_log[j]) * sp);
  }
}

// ---------------- in-place l2norm of q (scaled) and k heads ----------------
__global__ __launch_bounds__(256)
void k_l2n(u16* __restrict__ qkvz) {
  const int w = threadIdx.x >> 6, lane = threadIdx.x & 63;
  const int r = blockIdx.x * 4 + w;       // 0..131071
  const int isK = r >> 16;
  const int rr = r & 65535;
  const int t = rr >> 4, hd = rr & 15;
  u16* p = qkvz + (size_t)t * NTOT + isK * 2048 + hd * DKK + lane * 2;
  float a = b2f(p[0]), b = b2f(p[1]);
  float ss = a * a + b * b;
  ss = red16(ss);
  ss += __shfl_xor(ss, 16);
  ss += __shfl_xor(ss, 32);
  const float sc = rsqrtf(ss + 1e-6f) * (isK ? 1.f : 0.08838834764831845f); // q: *DK^-0.5
  p[0] = f2bf(a * sc); p[1] = f2bf(b * sc);
}

// ---------------- gated delta-rule recurrence ----------------
// block = (head hv, 16-column slice); 16 lanes per column x 8 state elems
__global__ __launch_bounds__(256)
void k_recur(const u16* __restrict__ qkvz, const float* __restrict__ beta,
             const float* __restrict__ decay, u16* __restrict__ coreT) {
  const int hv = blockIdx.x >> 3, vb = blockIdx.x & 7;
  const int hk = hv >> 1;
  const int li = threadIdx.x & 15, g = threadIdx.x >> 4;
  const int dv = vb * 16 + g;
  const u16* qp = qkvz + hk * DKK + li * 8;
  const u16* kp = qkvz + 2048 + hk * DKK + li * 8;
  const u16* vp = qkvz + 4096 + hv * DKK + dv;
  const float* bp = beta + hv;
  const float* dp = decay + hv;
  u16* op = coreT + (size_t)(hv * DKK + dv) * LTOK;
  float s[8];
#pragma unroll
  for (int j = 0; j < 8; ++j) s[j] = 0.f;
  u16x8 kc = *(const u16x8*)kp;
  u16x8 qc = *(const u16x8*)qp;
  float vc = b2f(*vp), bc = *bp, dc = *dp;
  float obuf = 0.f;
  for (int t = 0; t < LTOK; ++t) {
    const int tn = (t + 1 < LTOK) ? t + 1 : t;
    u16x8 kn = *(const u16x8*)(kp + (size_t)tn * NTOT);
    u16x8 qn = *(const u16x8*)(qp + (size_t)tn * NTOT);
    u16 vraw = vp[(size_t)tn * NTOT];
    float bn = bp[(size_t)tn * HVN];
    float dn = dp[(size_t)tn * HVN];
    float kf[8], qf[8];
#pragma unroll
    for (int j = 0; j < 8; ++j) { kf[j] = b2f(kc[j]); qf[j] = b2f(qc[j]); }
    float r = 0.f;
#pragma unroll
    for (int j = 0; j < 8; ++j) r = fmaf(kf[j], s[j], r);
    r = red16(r);                                   // k . s_pre (per column)
    const float delta = (vc - dc * r) * bc;         // (v - k.(d*s)) * beta
    float o = 0.f;
#pragma unroll
    for (int j = 0; j < 8; ++j) {
      s[j] = fmaf(dc, s[j], kf[j] * delta);         // s = d*s + k*delta
      o = fmaf(qf[j], s[j], o);
    }
    o = red16(o);                                   // q . s_new
    if ((t & 15) == li) obuf = o;
    if ((t & 15) == 15) op[t - 15 + li] = f2bf(obuf);  // coalesced 16-token flush
    kc = kn; qc = qn; vc = b2f(vraw); bc = bn; dc = dn;
  }
}

// ---------------- gated RMSNorm: x = rmsnorm(core * silu(z)) * w ----------------
__global__ __launch_bounds__(64)
void k_gnorm(const u16* __restrict__ coreT, const u16* __restrict__ qkvz,
             const float* __restrict__ nw, u16* __restrict__ x) {
  const int hv = blockIdx.y;
  const int t0 = blockIdx.x * 64;
  const int tid = threadIdx.x;
  __shared__ u16 zl[64][130];
  __shared__ float xl[64][129];
  const u16* zp = qkvz + 8192 + hv * DKK;
  for (int j = 0; j < 64; ++j) {
    const u16* srcp = zp + (size_t)(t0 + j) * NTOT + tid * 2;
    zl[j][tid * 2] = srcp[0];
    zl[j][tid * 2 + 1] = srcp[1];
  }
  __syncthreads();
  const u16* cp = coreT + (size_t)(hv * DKK) * LTOK + t0 + tid;
  float sum = 0.f;
  for (int c = 0; c < 128; ++c) {
    float cv = b2f(cp[(size_t)c * LTOK]);
    float z = b2f(zl[tid][c]);
    float xv = cv * (z / (1.f + __expf(-z)));
    xl[tid][c] = xv;
    sum = fmaf(xv, xv, sum);
  }
  const float scl = rsqrtf(sum * (1.f / 128.f) + 1e-6f);
  u16* xo = x + (size_t)(t0 + tid) * 4096 + hv * DKK;
  for (int c8 = 0; c8 < 16; ++c8) {
    u16x8 pk;
#pragma unroll
    for (int e = 0; e < 8; ++e) pk[e] = f2bf(xl[tid][c8 * 8 + e] * scl * nw[c8 * 8 + e]);
    *(u16x8*)(xo + c8 * 8) = pk;
  }
}

extern "C" void kernel_launch(void* const* d_in, const int* in_sizes, int n_in,
                              void* d_out, int out_size, void* d_ws, size_t ws_size,
                              hipStream_t stream) {
  const float* h    = (const float*)d_in[0];
  const float* Wq   = (const float*)d_in[1];
  const float* Wk   = (const float*)d_in[2];
  const float* Wv   = (const float*)d_in[3];
  const float* Wz   = (const float*)d_in[4];
  const float* Wb   = (const float*)d_in[5];
  const float* Wa   = (const float*)d_in[6];
  const float* Alog = (const float*)d_in[7];
  const float* dtb  = (const float*)d_in[8];
  const float* nw   = (const float*)d_in[9];
  const float* Wo   = (const float*)d_in[10];
  char* ws = (char*)d_ws;
  // layout (bytes): h_bf 16M | Wt_qkvz 48M(50.3) | Wt_out 16M | qkvz 96M(100.7) | coreT 32M | beta/decay 1M
  u16* h_bf  = (u16*)(ws);
  u16* Wt    = (u16*)(ws + 16777216ull);    // [12288][2048] bf16
  u16* Wto   = (u16*)(ws + 67108864ull);    // [2048][4096] bf16
  u16* qkvz  = (u16*)(ws + 83886080ull);    // [4096][12288] bf16
  u16* coreT = (u16*)(ws + 184549376ull);   // [4096 cols][4096 t] bf16
  u16* xbuf  = (u16*)(ws + 16777216ull);    // aliases Wt (dead after qkvz gemm)
  float* beta  = (float*)(ws + 218103808ull);
  float* decay = beta + (size_t)LTOK * HVN;

  k_cvt<<<8192, 256, 0, stream>>>(h, h_bf, LTOK * DHID);
  k_tr<<<dim3(64, 64), 256, 0, stream>>>(Wq, Wt, 2048, 2048);
  k_tr<<<dim3(64, 64), 256, 0, stream>>>(Wk, Wt + 2048ull * 2048, 2048, 2048);
  k_tr<<<dim3(128, 64), 256, 0, stream>>>(Wv, Wt + 4096ull * 2048, 2048, 4096);
  k_tr<<<dim3(128, 64), 256, 0, stream>>>(Wz, Wt + 8192ull * 2048, 2048, 4096);
  k_tr<<<dim3(64, 128), 256, 0, stream>>>(Wo, Wto, 4096, 2048);
  k_gemm<u16><<<dim3(96, 32), 256, 0, stream>>>(h_bf, Wt, qkvz, 4096, 12288, 2048);
  k_ba<<<1024, 256, 0, stream>>>(h, Wb, Wa, Alog, dtb, beta, decay);
  k_l2n<<<32768, 256, 0, stream>>>(qkvz);
  k_recur<<<256, 256, 0, stream>>>(qkvz, beta, decay, coreT);
  k_gnorm<<<dim3(64, 32), 64, 0, stream>>>(coreT, qkvz, nw, xbuf);
  k_gemm<float><<<dim3(16, 32), 256, 0, stream>>>(xbuf, Wto, (float*)d_out, 4096, 2048, 4096);
}

// Round 2
// 2090.508 us; speedup vs baseline: 1.1625x; 1.1625x over previous
//
#include <hip/hip_runtime.h>

#define LTOK 4096
#define DHID 2048
#define HKN  16
#define HVN  32
#define DKK  128
#define NTOT 12288

typedef unsigned short u16;
typedef __attribute__((ext_vector_type(8))) short short8;
typedef __attribute__((ext_vector_type(8))) unsigned short u16x8;
typedef __attribute__((ext_vector_type(4))) unsigned short u16x4;
typedef __attribute__((ext_vector_type(4))) float f32x4;

__device__ __forceinline__ float b2f(u16 u) {
  unsigned int x = ((unsigned int)u) << 16;
  return __builtin_bit_cast(float, x);
}
__device__ __forceinline__ u16 f2bf(float f) {
  unsigned int u = __builtin_bit_cast(unsigned int, f);
  u += 0x7FFFu + ((u >> 16) & 1u);
  return (u16)(u >> 16);
}

template<int C> __device__ __forceinline__ float dppmv(float x) {
  int i = __builtin_amdgcn_update_dpp(0, __builtin_bit_cast(int, x), C, 0xF, 0xF, true);
  return __builtin_bit_cast(float, i);
}
// all 16 lanes of each 16-lane row end with the row sum (4 DPP-latency ops)
__device__ __forceinline__ float red16(float x) {
  x += dppmv<0xB1>(x);   // quad_perm [1,0,3,2]
  x += dppmv<0x4E>(x);   // quad_perm [2,3,0,1]
  x += dppmv<0x124>(x);  // row_ror:4
  x += dppmv<0x128>(x);  // row_ror:8
  return x;
}
__device__ __forceinline__ float red32(float x) {
  x = red16(x);
  x += __shfl_xor(x, 16);
  return x;
}

__device__ __forceinline__ void gld16(const void* g, void* l) {
  __builtin_amdgcn_global_load_lds((const __attribute__((address_space(1))) void*)g,
                                   (__attribute__((address_space(3))) void*)l, 16, 0, 0);
}

__device__ __forceinline__ void cstore(u16* C, size_t i, float v) { C[i] = f2bf(v); }
__device__ __forceinline__ void cstore(float* C, size_t i, float v) { C[i] = v; }

// ---------------- fp32 -> bf16 convert ----------------
__global__ __launch_bounds__(256)
void k_cvt(const float* __restrict__ s, u16* __restrict__ d, int n) {
  const int i = (blockIdx.x * 256 + threadIdx.x) * 4;
  const float4 v = *(const float4*)(s + i);
  ushort4 o;
  o.x = f2bf(v.x); o.y = f2bf(v.y); o.z = f2bf(v.z); o.w = f2bf(v.w);
  *(ushort4*)(d + i) = o;
}

// ---------------- fp32 [R][C] -> bf16 [C][R] transpose ----------------
__global__ __launch_bounds__(256)
void k_tr(const float* __restrict__ src, u16* __restrict__ dst, int R, int C) {
  __shared__ float tl[32][33];
  const int r0 = blockIdx.y * 32, c0 = blockIdx.x * 32;
  const int tr = threadIdx.x >> 3, tc = (threadIdx.x & 7) * 4;
  const float4 v = *(const float4*)(src + (size_t)(r0 + tr) * C + c0 + tc);
  tl[tr][tc] = v.x; tl[tr][tc + 1] = v.y; tl[tr][tc + 2] = v.z; tl[tr][tc + 3] = v.w;
  __syncthreads();
  ushort4 o;
  o.x = f2bf(tl[tc + 0][tr]); o.y = f2bf(tl[tc + 1][tr]);
  o.z = f2bf(tl[tc + 2][tr]); o.w = f2bf(tl[tc + 3][tr]);
  *(ushort4*)(dst + (size_t)(c0 + tr) * R + r0 + tc) = o;
}

// ---------------- bf16 MFMA GEMM: C[M][N] = A[M][K] * Bt[N][K]^T ----------------
template<typename OutT>
__global__ __launch_bounds__(256, 2)
void k_gemm(const u16* __restrict__ A, const u16* __restrict__ Bt, OutT* __restrict__ C,
            int M, int N, int K) {
  __shared__ u16 lA[128 * 32];
  __shared__ u16 lB[128 * 32];
  const int tid = threadIdx.x;
  const int lane = tid & 63, wid = tid >> 6;
  const int nt = blockIdx.x, mt = blockIdx.y;
  const int wm = (wid >> 1) * 64, wn = (wid & 1) * 64;
  const size_t sK = (size_t)K;
  const u16* aS = A + (size_t)(mt * 128 + wid * 32 + (lane >> 2)) * sK + (lane & 3) * 8;
  const u16* bS = Bt + (size_t)(nt * 128 + wid * 32 + (lane >> 2)) * sK + (lane & 3) * 8;
  u16* lAw = lA + wid * 1024;  // wave-uniform LDS dest (1KB segs)
  u16* lBw = lB + wid * 1024;
  f32x4 acc[4][4] = {};
  const int aoff = (lane & 15) * 32 + (lane >> 4) * 8;

  for (int k0 = 0; k0 < K; k0 += 32) {
    gld16(aS + k0, lAw);
    gld16(aS + k0 + 16 * sK, lAw + 512);
    gld16(bS + k0, lBw);
    gld16(bS + k0 + 16 * sK, lBw + 512);
    __syncthreads();  // drains vmcnt -> LDS tile ready
    short8 af[4], bfv[4];
#pragma unroll
    for (int i = 0; i < 4; ++i) {
      af[i]  = *(const short8*)&lA[(wm + i * 16) * 32 + aoff];
      bfv[i] = *(const short8*)&lB[(wn + i * 16) * 32 + aoff];
    }
#pragma unroll
    for (int i = 0; i < 4; ++i)
#pragma unroll
      for (int j = 0; j < 4; ++j)
        acc[i][j] = __builtin_amdgcn_mfma_f32_16x16x32_bf16(af[i], bfv[j], acc[i][j], 0, 0, 0);
    __syncthreads();
  }
  const int r0 = mt * 128 + wm + (lane >> 4) * 4;
  const int c0 = nt * 128 + wn + (lane & 15);
#pragma unroll
  for (int i = 0; i < 4; ++i)
#pragma unroll
    for (int j = 0; j < 4; ++j)
#pragma unroll
      for (int e = 0; e < 4; ++e)
        cstore(C, (size_t)(r0 + i * 16 + e) * N + c0 + j * 16, acc[i][j][e]);
}

// ---------------- beta / decay: [L,2048]@[2048,32] x2 + activations ----------------
__global__ __launch_bounds__(256)
void k_ba(const float* __restrict__ h, const float* __restrict__ Wb, const float* __restrict__ Wa,
          const float* __restrict__ A_log, const float* __restrict__ dtb,
          float* __restrict__ beta, float* __restrict__ decay) {
  const int w = threadIdx.x >> 6, lane = threadIdx.x & 63;
  const int t = blockIdx.x * 4 + w;
  const int j = lane & 31;
  const bool isB = lane < 32;
  const float* __restrict__ hr = h + (size_t)t * DHID;
  const float* Wc = isB ? Wb : Wa;
  float acc = 0.f;
  for (int kk = 0; kk < DHID; ++kk) acc = fmaf(hr[kk], Wc[(size_t)kk * HVN + j], acc);
  if (isB) {
    beta[(size_t)t * HVN + j] = 1.f / (1.f + expf(-acc));
  } else {
    float xx = acc + dtb[j];
    float sp = (xx > 20.f) ? xx : log1pf(expf(xx));
    decay[(size_t)t * HVN + j] = expf(-expf(A_log[j]) * sp);
  }
}

// ---------------- in-place l2norm of q (scaled) and k heads ----------------
__global__ __launch_bounds__(256)
void k_l2n(u16* __restrict__ qkvz) {
  const int w = threadIdx.x >> 6, lane = threadIdx.x & 63;
  const int r = blockIdx.x * 4 + w;       // 0..131071
  const int isK = r >> 16;
  const int rr = r & 65535;
  const int t = rr >> 4, hd = rr & 15;
  u16* p = qkvz + (size_t)t * NTOT + isK * 2048 + hd * DKK + lane * 2;
  float a = b2f(p[0]), b = b2f(p[1]);
  float ss = a * a + b * b;
  ss = red16(ss);
  ss += __shfl_xor(ss, 16);
  ss += __shfl_xor(ss, 32);
  const float sc = rsqrtf(ss + 1e-6f) * (isK ? 1.f : 0.08838834764831845f); // q: *DK^-0.5
  p[0] = f2bf(a * sc); p[1] = f2bf(b * sc);
}

// ---------------- gated delta-rule recurrence ----------------
// block = (head hv, 8-column slice); 32 lanes per column x 4 state elems/lane
// 512 blocks x 256 thr = 2048 waves = 2 waves/SIMD; depth-3 register pipeline
__global__ __launch_bounds__(256)
void k_recur(const u16* __restrict__ qkvz, const float* __restrict__ beta,
             const float* __restrict__ decay, u16* __restrict__ coreT) {
  const int hv = blockIdx.x >> 4, vb = blockIdx.x & 15;
  const int hk = hv >> 1;
  const int li = threadIdx.x & 31, g = threadIdx.x >> 5;   // g in 0..7
  const int dv = vb * 8 + g;
  const u16* qp = qkvz + hk * DKK + li * 4;
  const u16* kp = qkvz + 2048 + hk * DKK + li * 4;
  const u16* vp = qkvz + 4096 + hv * DKK + dv;
  const float* bp = beta + hv;
  const float* dp = decay + hv;
  u16* op = coreT + (size_t)(hv * DKK + dv) * LTOK;
  float s0 = 0.f, s1 = 0.f, s2 = 0.f, s3 = 0.f;
  float obuf = 0.f;
  u16x4 kA, qA, kB, qB, kC, qC;
  u16 vA, vB, vC;
  float bA, dA, bB, dB, bC, dC;

#define RLOAD(K, Q, V, B, D, tt) {                                            \
    const size_t tc = (size_t)(((tt) < LTOK) ? (tt) : (LTOK - 1));            \
    K = *(const u16x4*)(kp + tc * NTOT);                                      \
    Q = *(const u16x4*)(qp + tc * NTOT);                                      \
    V = vp[tc * NTOT];                                                        \
    B = bp[tc * HVN];                                                         \
    D = dp[tc * HVN]; }

#define RSTEP(K, Q, V, B, D, tt) {                                            \
    const float kf0 = b2f(K[0]), kf1 = b2f(K[1]), kf2 = b2f(K[2]), kf3 = b2f(K[3]); \
    float r = kf0 * s0;                                                       \
    r = fmaf(kf1, s1, r); r = fmaf(kf2, s2, r); r = fmaf(kf3, s3, r);         \
    r = red32(r);                                                             \
    const float dl = (b2f(V) - D * r) * B;                                    \
    s0 = fmaf(D, s0, kf0 * dl); s1 = fmaf(D, s1, kf1 * dl);                   \
    s2 = fmaf(D, s2, kf2 * dl); s3 = fmaf(D, s3, kf3 * dl);                   \
    float o = b2f(Q[0]) * s0;                                                 \
    o = fmaf(b2f(Q[1]), s1, o); o = fmaf(b2f(Q[2]), s2, o); o = fmaf(b2f(Q[3]), s3, o); \
    o = red32(o);                                                             \
    if (((tt) & 31) == li) obuf = o;                                          \
    if (((tt) & 31) == 31) op[(tt) - 31 + li] = f2bf(obuf); }

  RLOAD(kA, qA, vA, bA, dA, 0)
  RLOAD(kB, qB, vB, bB, dB, 1)
  RLOAD(kC, qC, vC, bC, dC, 2)
  for (int t = 0; t < LTOK - 1; t += 3) {   // tokens 0..4094 (1365 iters)
    RSTEP(kA, qA, vA, bA, dA, t)
    RLOAD(kA, qA, vA, bA, dA, t + 3)
    RSTEP(kB, qB, vB, bB, dB, t + 1)
    RLOAD(kB, qB, vB, bB, dB, t + 4)
    RSTEP(kC, qC, vC, bC, dC, t + 2)
    RLOAD(kC, qC, vC, bC, dC, t + 5)
  }
  RSTEP(kA, qA, vA, bA, dA, LTOK - 1)       // token 4095
#undef RLOAD
#undef RSTEP
}

// ---------------- gated RMSNorm: x = rmsnorm(core * silu(z)) * w ----------------
__global__ __launch_bounds__(64)
void k_gnorm(const u16* __restrict__ coreT, const u16* __restrict__ qkvz,
             const float* __restrict__ nw, u16* __restrict__ x) {
  const int hv = blockIdx.y;
  const int t0 = blockIdx.x * 64;
  const int tid = threadIdx.x;
  __shared__ u16 zl[64][130];
  __shared__ float xl[64][129];
  const u16* zp = qkvz + 8192 + hv * DKK;
  for (int j = 0; j < 64; ++j) {
    const u16* srcp = zp + (size_t)(t0 + j) * NTOT + tid * 2;
    zl[j][tid * 2] = srcp[0];
    zl[j][tid * 2 + 1] = srcp[1];
  }
  __syncthreads();
  const u16* cp = coreT + (size_t)(hv * DKK) * LTOK + t0 + tid;
  float sum = 0.f;
  for (int c = 0; c < 128; ++c) {
    float cv = b2f(cp[(size_t)c * LTOK]);
    float z = b2f(zl[tid][c]);
    float xv = cv * (z / (1.f + __expf(-z)));
    xl[tid][c] = xv;
    sum = fmaf(xv, xv, sum);
  }
  const float scl = rsqrtf(sum * (1.f / 128.f) + 1e-6f);
  u16* xo = x + (size_t)(t0 + tid) * 4096 + hv * DKK;
  for (int c8 = 0; c8 < 16; ++c8) {
    u16x8 pk;
#pragma unroll
    for (int e = 0; e < 8; ++e) pk[e] = f2bf(xl[tid][c8 * 8 + e] * scl * nw[c8 * 8 + e]);
    *(u16x8*)(xo + c8 * 8) = pk;
  }
}

extern "C" void kernel_launch(void* const* d_in, const int* in_sizes, int n_in,
                              void* d_out, int out_size, void* d_ws, size_t ws_size,
                              hipStream_t stream) {
  const float* h    = (const float*)d_in[0];
  const float* Wq   = (const float*)d_in[1];
  const float* Wk   = (const float*)d_in[2];
  const float* Wv   = (const float*)d_in[3];
  const float* Wz   = (const float*)d_in[4];
  const float* Wb   = (const float*)d_in[5];
  const float* Wa   = (const float*)d_in[6];
  const float* Alog = (const float*)d_in[7];
  const float* dtb  = (const float*)d_in[8];
  const float* nw   = (const float*)d_in[9];
  const float* Wo   = (const float*)d_in[10];
  char* ws = (char*)d_ws;
  // layout (bytes): h_bf 16M | Wt_qkvz 48M(50.3) | Wt_out 16M | qkvz 96M(100.7) | coreT 32M | beta/decay 1M
  u16* h_bf  = (u16*)(ws);
  u16* Wt    = (u16*)(ws + 16777216ull);    // [12288][2048] bf16
  u16* Wto   = (u16*)(ws + 67108864ull);    // [2048][4096] bf16
  u16* qkvz  = (u16*)(ws + 83886080ull);    // [4096][12288] bf16
  u16* coreT = (u16*)(ws + 184549376ull);   // [4096 cols][4096 t] bf16
  u16* xbuf  = (u16*)(ws + 16777216ull);    // aliases Wt (dead after qkvz gemm)
  float* beta  = (float*)(ws + 218103808ull);
  float* decay = beta + (size_t)LTOK * HVN;

  k_cvt<<<8192, 256, 0, stream>>>(h, h_bf, LTOK * DHID);
  k_tr<<<dim3(64, 64), 256, 0, stream>>>(Wq, Wt, 2048, 2048);
  k_tr<<<dim3(64, 64), 256, 0, stream>>>(Wk, Wt + 2048ull * 2048, 2048, 2048);
  k_tr<<<dim3(128, 64), 256, 0, stream>>>(Wv, Wt + 4096ull * 2048, 2048, 4096);
  k_tr<<<dim3(128, 64), 256, 0, stream>>>(Wz, Wt + 8192ull * 2048, 2048, 4096);
  k_tr<<<dim3(64, 128), 256, 0, stream>>>(Wo, Wto, 4096, 2048);
  k_gemm<u16><<<dim3(96, 32), 256, 0, stream>>>(h_bf, Wt, qkvz, 4096, 12288, 2048);
  k_ba<<<1024, 256, 0, stream>>>(h, Wb, Wa, Alog, dtb, beta, decay);
  k_l2n<<<32768, 256, 0, stream>>>(qkvz);
  k_recur<<<512, 256, 0, stream>>>(qkvz, beta, decay, coreT);
  k_gnorm<<<dim3(64, 32), 64, 0, stream>>>(coreT, qkvz, nw, xbuf);
  k_gemm<float><<<dim3(16, 32), 256, 0, stream>>>(xbuf, Wto, (float*)d_out, 4096, 2048, 4096);
}

// Round 3
// 1002.927 us; speedup vs baseline: 2.4230x; 2.0844x over previous
//
#include <hip/hip_runtime.h>

#define LTOK 4096
#define DHID 2048
#define HKN  16
#define HVN  32
#define DKK  128
#define NTOT 12288

typedef unsigned short u16;
typedef __attribute__((ext_vector_type(8))) short short8;
typedef __attribute__((ext_vector_type(8))) unsigned short u16x8;
typedef __attribute__((ext_vector_type(4))) unsigned short u16x4;
typedef __attribute__((ext_vector_type(4))) float f32x4;

__device__ __forceinline__ float b2f(u16 u) {
  unsigned int x = ((unsigned int)u) << 16;
  return __builtin_bit_cast(float, x);
}
__device__ __forceinline__ u16 f2bf(float f) {
  unsigned int u = __builtin_bit_cast(unsigned int, f);
  u += 0x7FFFu + ((u >> 16) & 1u);
  return (u16)(u >> 16);
}

template<int C> __device__ __forceinline__ float dppmv(float x) {
  int i = __builtin_amdgcn_update_dpp(0, __builtin_bit_cast(int, x), C, 0xF, 0xF, true);
  return __builtin_bit_cast(float, i);
}
__device__ __forceinline__ float red16(float x) {
  x += dppmv<0xB1>(x);
  x += dppmv<0x4E>(x);
  x += dppmv<0x124>(x);
  x += dppmv<0x128>(x);
  return x;
}

__device__ __forceinline__ void gld16(const void* g, void* l) {
  __builtin_amdgcn_global_load_lds((const __attribute__((address_space(1))) void*)g,
                                   (__attribute__((address_space(3))) void*)l, 16, 0, 0);
}

// swizzled LDS element offsets (XOR row-bits into 16B-slot bits); byte^=((r&7)<<4)
__device__ __forceinline__ int sw16(int r, int c, int rowc) { return (r * rowc + c) ^ ((r & 7) << 3); }
__device__ __forceinline__ int sw32(int r, int c, int rowc) { return (r * rowc + c) ^ ((r & 7) << 2); }

__device__ __forceinline__ void cstore(u16* C, size_t i, float v) { C[i] = f2bf(v); }
__device__ __forceinline__ void cstore(float* C, size_t i, float v) { C[i] = v; }

// ---------------- fp32 -> bf16 convert ----------------
__global__ __launch_bounds__(256)
void k_cvt(const float* __restrict__ s, u16* __restrict__ d, int n) {
  const int i = (blockIdx.x * 256 + threadIdx.x) * 4;
  const float4 v = *(const float4*)(s + i);
  ushort4 o;
  o.x = f2bf(v.x); o.y = f2bf(v.y); o.z = f2bf(v.z); o.w = f2bf(v.w);
  *(ushort4*)(d + i) = o;
}

// ---------------- fp32 [R][C] -> bf16 [C][R] transpose ----------------
__global__ __launch_bounds__(256)
void k_tr(const float* __restrict__ src, u16* __restrict__ dst, int R, int C) {
  __shared__ float tl[32][33];
  const int r0 = blockIdx.y * 32, c0 = blockIdx.x * 32;
  const int tr = threadIdx.x >> 3, tc = (threadIdx.x & 7) * 4;
  const float4 v = *(const float4*)(src + (size_t)(r0 + tr) * C + c0 + tc);
  tl[tr][tc] = v.x; tl[tr][tc + 1] = v.y; tl[tr][tc + 2] = v.z; tl[tr][tc + 3] = v.w;
  __syncthreads();
  ushort4 o;
  o.x = f2bf(tl[tc + 0][tr]); o.y = f2bf(tl[tc + 1][tr]);
  o.z = f2bf(tl[tc + 2][tr]); o.w = f2bf(tl[tc + 3][tr]);
  *(ushort4*)(dst + (size_t)(c0 + tr) * R + r0 + tc) = o;
}

// ---------------- bf16 MFMA GEMM: C[M][N] = A[M][K] * Bt[N][K]^T ----------------
template<typename OutT>
__global__ __launch_bounds__(256, 2)
void k_gemm(const u16* __restrict__ A, const u16* __restrict__ Bt, OutT* __restrict__ C,
            int M, int N, int K) {
  __shared__ u16 lA[128 * 32];
  __shared__ u16 lB[128 * 32];
  const int tid = threadIdx.x;
  const int lane = tid & 63, wid = tid >> 6;
  const int nt = blockIdx.x, mt = blockIdx.y;
  const int wm = (wid >> 1) * 64, wn = (wid & 1) * 64;
  const size_t sK = (size_t)K;
  const u16* aS = A + (size_t)(mt * 128 + wid * 32 + (lane >> 2)) * sK + (lane & 3) * 8;
  const u16* bS = Bt + (size_t)(nt * 128 + wid * 32 + (lane >> 2)) * sK + (lane & 3) * 8;
  u16* lAw = lA + wid * 1024;
  u16* lBw = lB + wid * 1024;
  f32x4 acc[4][4] = {};
  const int aoff = (lane & 15) * 32 + (lane >> 4) * 8;

  for (int k0 = 0; k0 < K; k0 += 32) {
    gld16(aS + k0, lAw);
    gld16(aS + k0 + 16 * sK, lAw + 512);
    gld16(bS + k0, lBw);
    gld16(bS + k0 + 16 * sK, lBw + 512);
    __syncthreads();
    short8 af[4], bfv[4];
#pragma unroll
    for (int i = 0; i < 4; ++i) {
      af[i]  = *(const short8*)&lA[(wm + i * 16) * 32 + aoff];
      bfv[i] = *(const short8*)&lB[(wn + i * 16) * 32 + aoff];
    }
#pragma unroll
    for (int i = 0; i < 4; ++i)
#pragma unroll
      for (int j = 0; j < 4; ++j)
        acc[i][j] = __builtin_amdgcn_mfma_f32_16x16x32_bf16(af[i], bfv[j], acc[i][j], 0, 0, 0);
    __syncthreads();
  }
  const int r0 = mt * 128 + wm + (lane >> 4) * 4;
  const int c0 = nt * 128 + wn + (lane & 15);
#pragma unroll
  for (int i = 0; i < 4; ++i)
#pragma unroll
    for (int j = 0; j < 4; ++j)
#pragma unroll
      for (int e = 0; e < 4; ++e)
        cstore(C, (size_t)(r0 + i * 16 + e) * N + c0 + j * 16, acc[i][j][e]);
}

// ---------------- beta / g (log-decay): [L,2048]@[2048,32] x2 + activations ----------------
__global__ __launch_bounds__(256)
void k_ba(const float* __restrict__ h, const float* __restrict__ Wb, const float* __restrict__ Wa,
          const float* __restrict__ A_log, const float* __restrict__ dtb,
          float* __restrict__ beta, float* __restrict__ g_out) {
  const int w = threadIdx.x >> 6, lane = threadIdx.x & 63;
  const int t = blockIdx.x * 4 + w;
  const int j = lane & 31;
  const bool isB = lane < 32;
  const float* __restrict__ hr = h + (size_t)t * DHID;
  const float* Wc = isB ? Wb : Wa;
  float acc = 0.f;
  for (int kk = 0; kk < DHID; ++kk) acc = fmaf(hr[kk], Wc[(size_t)kk * HVN + j], acc);
  if (isB) {
    beta[(size_t)t * HVN + j] = 1.f / (1.f + expf(-acc));
  } else {
    float xx = acc + dtb[j];
    float sp = (xx > 20.f) ? xx : log1pf(expf(xx));
    g_out[(size_t)t * HVN + j] = -expf(A_log[j]) * sp;   // g = log(decay) <= 0
  }
}

// ---------------- in-place l2norm of q (scaled) and k heads ----------------
__global__ __launch_bounds__(256)
void k_l2n(u16* __restrict__ qkvz) {
  const int w = threadIdx.x >> 6, lane = threadIdx.x & 63;
  const int r = blockIdx.x * 4 + w;
  const int isK = r >> 16;
  const int rr = r & 65535;
  const int t = rr >> 4, hd = rr & 15;
  u16* p = qkvz + (size_t)t * NTOT + isK * 2048 + hd * DKK + lane * 2;
  float a = b2f(p[0]), b = b2f(p[1]);
  float ss = a * a + b * b;
  ss = red16(ss);
  ss += __shfl_xor(ss, 16);
  ss += __shfl_xor(ss, 32);
  const float sc = rsqrtf(ss + 1e-6f) * (isK ? 1.f : 0.08838834764831845f);
  p[0] = f2bf(a * sc); p[1] = f2bf(b * sc);
}

#define MFMA16(a, b, c) __builtin_amdgcn_mfma_f32_16x16x32_bf16(a, b, c, 0, 0, 0)

// ---------------- chunk solve (parallel): per (hv, chunk n) ----------------
// Solves (I+N)[U|M] = [beta*v | beta*e^L*k]; N[t][s]=beta_t e^{Lt-Ls}(kt.ks), s<t.
// Exact Neumann doubling with D=-N (nilpotent): X <- (I+D)(I+D2)...(I+D32) rhs.
// Stores U (cols 0..127) and -M (cols 128..255) bf16, plus cumL per chunk.
__global__ __launch_bounds__(256)
void k_r1(const u16* __restrict__ qkvz, const float* __restrict__ beta_g,
          const float* __restrict__ g_g, u16* __restrict__ UM_g, float* __restrict__ cumL_g) {
  const int pair = blockIdx.x;          // hv*64 + n
  const int hv = pair >> 6, n = pair & 63;
  const int hk = hv >> 1;
  const int t0 = n * 64;
  const int tid = threadIdx.x, lane = tid & 63, wv = tid >> 6;
  const int fr = lane & 15, fq = lane >> 4;

  __shared__ __align__(16) u16 Xb[256 * 64];     // X^T [c][s] bf16, rowc=64, swz
  __shared__ __align__(16) u16 Dbuf0[64 * 64 * 2]; // Dr+Dc (aliases Kl first)
  __shared__ __align__(16) u16 Dbuf1[64 * 64 * 2];
  __shared__ float Lc[64];
  __shared__ float Bc[64];
  u16* Kl = Dbuf0;                                // [64][128] rowc=128, swz

  // ---- P0: stage K,V to regs, raw g/beta to LDS, write Kl ----
  const int j = tid & 63, h = tid >> 6;
  const u16* kg = qkvz + (size_t)(t0 + j) * NTOT + 2048 + hk * DKK + h * 32;
  const u16* vg = qkvz + (size_t)(t0 + j) * NTOT + 4096 + hv * DKK + h * 32;
  u16x8 kv[4], vv[4];
#pragma unroll
  for (int i = 0; i < 4; ++i) { kv[i] = *(const u16x8*)(kg + i * 8); vv[i] = *(const u16x8*)(vg + i * 8); }
  if (tid < 64) {
    Lc[tid] = g_g[(size_t)(t0 + tid) * HVN + hv];
    Bc[tid] = beta_g[(size_t)(t0 + tid) * HVN + hv];
  }
#pragma unroll
  for (int i = 0; i < 4; ++i) *(u16x8*)&Kl[sw16(j, h * 32 + i * 8, 128)] = kv[i];
  __syncthreads();
  if (tid == 0) { float a = 0.f; for (int t = 0; t < 64; ++t) { a += Lc[t]; Lc[t] = a; } }
  __syncthreads();
  if (tid < 64) cumL_g[(size_t)pair * 64 + tid] = Lc[tid];

  // ---- P1: build rhs in Xb; KK^T MFMA ----
  {
    const float bj = Bc[j];
    const float mj = bj * __expf(Lc[j]);
#pragma unroll
    for (int i = 0; i < 4; ++i)
#pragma unroll
      for (int e = 0; e < 8; ++e) {
        int c = h * 32 + i * 8 + e;
        Xb[sw16(c, j, 64)] = f2bf(bj * b2f(vv[i][e]));
        Xb[sw16(128 + c, j, 64)] = f2bf(mj * b2f(kv[i][e]));
      }
  }
  f32x4 kk[4] = {};
#pragma unroll
  for (int ks = 0; ks < 4; ++ks) {
    short8 afr = *(const short8*)&Kl[sw16(wv * 16 + fr, ks * 32 + fq * 8, 128)];
#pragma unroll
    for (int ct = 0; ct < 4; ++ct) {
      short8 bfr = *(const short8*)&Kl[sw16(ct * 16 + fr, ks * 32 + fq * 8, 128)];
      kk[ct] = MFMA16(afr, bfr, kk[ct]);
    }
  }
  __syncthreads();

  // ---- P2: acc init from Xb; write D1 (over Kl) ----
  f32x4 acc[16];
#pragma unroll
  for (int ct = 0; ct < 16; ++ct) {
    u16x4 xi = *(const u16x4*)&Xb[sw16(ct * 16 + fr, wv * 16 + fq * 4, 64)];
    acc[ct][0] = b2f(xi[0]); acc[ct][1] = b2f(xi[1]); acc[ct][2] = b2f(xi[2]); acc[ct][3] = b2f(xi[3]);
  }
#pragma unroll
  for (int ct = 0; ct < 4; ++ct) {
    const int s = ct * 16 + fr;
    u16x4 pk;
#pragma unroll
    for (int e = 0; e < 4; ++e) {
      const int t = wv * 16 + fq * 4 + e;
      float v = (s < t) ? -Bc[t] * __expf(Lc[t] - Lc[s]) * kk[ct][e] : 0.f;
      pk[e] = f2bf(v);
      Dbuf0[sw16(t, s, 64)] = pk[e];                       // Dr
    }
    *(u16x4*)&Dbuf0[4096 + sw16(s, wv * 16 + fq * 4, 64)] = pk;  // Dc
  }
  __syncthreads();

  // ---- P3: 6 stages: X += D@X; D' = D@D (ping-pong) ----
  u16* DA = Dbuf0;
  u16* DB = Dbuf1;
  for (int stg = 0; stg < 6; ++stg) {
    u16* Dr = DA;
    u16* Dc = DA + 4096;
    short8 da0 = *(const short8*)&Dr[sw16(wv * 16 + fr, 0 + fq * 8, 64)];
    short8 da1 = *(const short8*)&Dr[sw16(wv * 16 + fr, 32 + fq * 8, 64)];
#pragma unroll
    for (int ct = 0; ct < 16; ++ct) {
      short8 b0 = *(const short8*)&Xb[sw16(ct * 16 + fr, 0 + fq * 8, 64)];
      short8 b1 = *(const short8*)&Xb[sw16(ct * 16 + fr, 32 + fq * 8, 64)];
      acc[ct] = MFMA16(da0, b0, acc[ct]);
      acc[ct] = MFMA16(da1, b1, acc[ct]);
    }
    f32x4 sq[4] = {};
    if (stg < 5) {
#pragma unroll
      for (int ct = 0; ct < 4; ++ct) {
        short8 sb0 = *(const short8*)&Dc[sw16(ct * 16 + fr, 0 + fq * 8, 64)];
        short8 sb1 = *(const short8*)&Dc[sw16(ct * 16 + fr, 32 + fq * 8, 64)];
        sq[ct] = MFMA16(da0, sb0, sq[ct]);
        sq[ct] = MFMA16(da1, sb1, sq[ct]);
      }
    }
    __syncthreads();   // all reads of Xb / D done
#pragma unroll
    for (int ct = 0; ct < 16; ++ct) {
      u16x4 pk;
      pk[0] = f2bf(acc[ct][0]); pk[1] = f2bf(acc[ct][1]); pk[2] = f2bf(acc[ct][2]); pk[3] = f2bf(acc[ct][3]);
      *(u16x4*)&Xb[sw16(ct * 16 + fr, wv * 16 + fq * 4, 64)] = pk;
    }
    if (stg < 5) {
#pragma unroll
      for (int ct = 0; ct < 4; ++ct) {
        u16x4 pk;
        pk[0] = f2bf(sq[ct][0]); pk[1] = f2bf(sq[ct][1]); pk[2] = f2bf(sq[ct][2]); pk[3] = f2bf(sq[ct][3]);
        *(u16x4*)&(DB + 4096)[sw16(ct * 16 + fr, wv * 16 + fq * 4, 64)] = pk;
#pragma unroll
        for (int e = 0; e < 4; ++e) DB[sw16(wv * 16 + fq * 4 + e, ct * 16 + fr, 64)] = pk[e];
      }
    }
    __syncthreads();
    u16* tmp = DA; DA = DB; DB = tmp;
  }

  // ---- store U | -M ----
#pragma unroll
  for (int ct = 0; ct < 16; ++ct) {
    const int c = ct * 16 + fr;
#pragma unroll
    for (int e = 0; e < 4; ++e) {
      const int t = wv * 16 + fq * 4 + e;
      float v = acc[ct][e];
      if (ct >= 8) v = -v;          // store -M so R2 can accumulate with MFMA (+)
      UM_g[((size_t)pair * 64 + t) * 256 + c] = f2bf(v);
    }
  }
}

// ---------------- sequential chunk scan: per (hv, dv-slice of 32) ----------------
// S[128][32] f32 carried in LDS; per chunk: delta = U + (-M)@S ; o = e^{Lt}(Q@S)+G@delta ;
// S = e^{L63} S + Kbar^T @ delta.
__global__ __launch_bounds__(256)
void k_r2(const u16* __restrict__ qkvz, const u16* __restrict__ UM_g,
          const float* __restrict__ cumL_g, u16* __restrict__ core) {
  const int hv = blockIdx.x >> 2, sl = blockIdx.x & 3;
  const int hk = hv >> 1, c0 = sl * 32;
  const int tid = threadIdx.x, lane = tid & 63, wv = tid >> 6;
  const int fr = lane & 15, fq = lane >> 4;
  const int j = tid & 63, h = tid >> 6;

  __shared__ __align__(16) u16 Ml[64 * 128];   // -M [t][c] swz rowc=128
  __shared__ __align__(16) u16 Ql[64 * 128];   // raw q
  __shared__ __align__(16) u16 Kl[64 * 128];   // raw k
  __shared__ __align__(16) u16 Kt[128 * 64];   // Kbar^T [dk][t] rowc=64
  __shared__ __align__(16) u16 Gl[64 * 64];    // G [t][s] rowc=64
  __shared__ __align__(16) u16 dT[32 * 64];    // delta^T [dv][t] rowc=64
  __shared__ __align__(16) float Ul[32 * 64];  // U^T slice [dv][t] f32 rowc=64
  __shared__ __align__(16) float SfT[32 * 128];// S^T [dv][dk] f32 rowc=128
  __shared__ __align__(16) u16 SbT[32 * 128];  // S^T bf16
  __shared__ float Lc[64];

  for (int i = tid; i < 32 * 128; i += 256) { SfT[i] = 0.f; SbT[i] = 0; }
  __syncthreads();

  for (int n = 0; n < 64; ++n) {
    const int pair = hv * 64 + n, t0 = n * 64;
    // ---- stage ----
    if (tid < 64) Lc[tid] = cumL_g[(size_t)pair * 64 + tid];
    const float Lj = cumL_g[(size_t)pair * 64 + j];
    const float L63 = cumL_g[(size_t)pair * 64 + 63];
    {
      const u16* mg = UM_g + ((size_t)pair * 64 + j) * 256 + 128 + h * 32;
      const u16* qg = qkvz + (size_t)(t0 + j) * NTOT + hk * DKK + h * 32;
      const u16* kg = qkvz + (size_t)(t0 + j) * NTOT + 2048 + hk * DKK + h * 32;
      const float sc = __expf(L63 - Lj);
#pragma unroll
      for (int i = 0; i < 4; ++i) {
        *(u16x8*)&Ml[sw16(j, h * 32 + i * 8, 128)] = *(const u16x8*)(mg + i * 8);
        *(u16x8*)&Ql[sw16(j, h * 32 + i * 8, 128)] = *(const u16x8*)(qg + i * 8);
        u16x8 kv8 = *(const u16x8*)(kg + i * 8);
        *(u16x8*)&Kl[sw16(j, h * 32 + i * 8, 128)] = kv8;
#pragma unroll
        for (int e = 0; e < 8; ++e) Kt[sw16(h * 32 + i * 8 + e, j, 64)] = f2bf(sc * b2f(kv8[e]));
      }
      const u16* ug = UM_g + ((size_t)pair * 64 + j) * 256 + c0 + h * 8;
      u16x8 uv = *(const u16x8*)ug;
#pragma unroll
      for (int e = 0; e < 8; ++e) Ul[sw32(h * 8 + e, j, 64)] = b2f(uv[e]);
    }
    __syncthreads();

    // ---- ph1: o_qs = (Q@S)*e^{Lt}; QK^T -> G; delta = U + (-M)@S -> dT ----
    short8 aq[4];
#pragma unroll
    for (int ks = 0; ks < 4; ++ks) aq[ks] = *(const short8*)&Ql[sw16(wv * 16 + fr, ks * 32 + fq * 8, 128)];
    f32x4 oacc[2];
#pragma unroll
    for (int ct = 0; ct < 2; ++ct) {
      f32x4 z = {};
#pragma unroll
      for (int ks = 0; ks < 4; ++ks) {
        short8 bs = *(const short8*)&SbT[sw16(ct * 16 + fr, ks * 32 + fq * 8, 128)];
        z = MFMA16(aq[ks], bs, z);
      }
      oacc[ct] = z;
    }
    float el[4];
#pragma unroll
    for (int e = 0; e < 4; ++e) el[e] = __expf(Lc[wv * 16 + fq * 4 + e]);
#pragma unroll
    for (int ct = 0; ct < 2; ++ct)
#pragma unroll
      for (int e = 0; e < 4; ++e) oacc[ct][e] *= el[e];

    f32x4 kkf[4] = {};
#pragma unroll
    for (int ks = 0; ks < 4; ++ks)
#pragma unroll
      for (int ct = 0; ct < 4; ++ct) {
        short8 bk = *(const short8*)&Kl[sw16(ct * 16 + fr, ks * 32 + fq * 8, 128)];
        kkf[ct] = MFMA16(aq[ks], bk, kkf[ct]);
      }
#pragma unroll
    for (int ct = 0; ct < 4; ++ct) {
      const int s = ct * 16 + fr;
#pragma unroll
      for (int e = 0; e < 4; ++e) {
        const int t = wv * 16 + fq * 4 + e;
        float v = (s <= t) ? kkf[ct][e] * __expf(Lc[t] - Lc[s]) : 0.f;
        Gl[sw16(t, s, 64)] = f2bf(v);
      }
    }
    {
      short8 am[4];
#pragma unroll
      for (int ks = 0; ks < 4; ++ks) am[ks] = *(const short8*)&Ml[sw16(wv * 16 + fr, ks * 32 + fq * 8, 128)];
#pragma unroll
      for (int ct = 0; ct < 2; ++ct) {
        f32x4 ci = *(const f32x4*)&Ul[sw32(ct * 16 + fr, wv * 16 + fq * 4, 64)];
#pragma unroll
        for (int ks = 0; ks < 4; ++ks) {
          short8 bs = *(const short8*)&SbT[sw16(ct * 16 + fr, ks * 32 + fq * 8, 128)];
          ci = MFMA16(am[ks], bs, ci);
        }
        u16x4 pk;
        pk[0] = f2bf(ci[0]); pk[1] = f2bf(ci[1]); pk[2] = f2bf(ci[2]); pk[3] = f2bf(ci[3]);
        *(u16x4*)&dT[sw16(ct * 16 + fr, wv * 16 + fq * 4, 64)] = pk;
      }
    }
    __syncthreads();

    // ---- ph3: o += G@delta, store; S = e^{L63} S + Kt@delta ----
#pragma unroll
    for (int ct = 0; ct < 2; ++ct) {
#pragma unroll
      for (int ks = 0; ks < 2; ++ks) {
        short8 ag = *(const short8*)&Gl[sw16(wv * 16 + fr, ks * 32 + fq * 8, 64)];
        short8 bd = *(const short8*)&dT[sw16(ct * 16 + fr, ks * 32 + fq * 8, 64)];
        oacc[ct] = MFMA16(ag, bd, oacc[ct]);
      }
#pragma unroll
      for (int e = 0; e < 4; ++e) {
        const int t = wv * 16 + fq * 4 + e, dv = ct * 16 + fr;
        core[(size_t)(t0 + t) * 4096 + hv * DKK + c0 + dv] = f2bf(oacc[ct][e]);
      }
    }
    const float eC = __expf(Lc[63]);
#pragma unroll
    for (int rt = 0; rt < 2; ++rt) {
      const int dkb = wv * 32 + rt * 16;
      short8 ak0 = *(const short8*)&Kt[sw16(dkb + fr, 0 + fq * 8, 64)];
      short8 ak1 = *(const short8*)&Kt[sw16(dkb + fr, 32 + fq * 8, 64)];
#pragma unroll
      for (int ct = 0; ct < 2; ++ct) {
        const int dv = ct * 16 + fr;
        f32x4 ci = *(const f32x4*)&SfT[sw32(dv, dkb + fq * 4, 128)];
#pragma unroll
        for (int e = 0; e < 4; ++e) ci[e] *= eC;
        short8 bd0 = *(const short8*)&dT[sw16(dv, 0 + fq * 8, 64)];
        short8 bd1 = *(const short8*)&dT[sw16(dv, 32 + fq * 8, 64)];
        ci = MFMA16(ak0, bd0, ci);
        ci = MFMA16(ak1, bd1, ci);
        *(f32x4*)&SfT[sw32(dv, dkb + fq * 4, 128)] = ci;
        u16x4 pk;
        pk[0] = f2bf(ci[0]); pk[1] = f2bf(ci[1]); pk[2] = f2bf(ci[2]); pk[3] = f2bf(ci[3]);
        *(u16x4*)&SbT[sw16(dv, dkb + fq * 4, 128)] = pk;
      }
    }
    __syncthreads();
  }
}

// ---------------- gated RMSNorm: x = rmsnorm(core * silu(z)) * w ----------------
__global__ __launch_bounds__(256)
void k_gnorm(const u16* __restrict__ core, const u16* __restrict__ qkvz,
             const float* __restrict__ nw, u16* __restrict__ x) {
  const int hv = blockIdx.y;
  const int t = blockIdx.x * 64 + (threadIdx.x >> 2);
  const int q = threadIdx.x & 3;
  const u16* cp = core + (size_t)t * 4096 + hv * DKK + q * 32;
  const u16* zp = qkvz + (size_t)t * NTOT + 8192 + hv * DKK + q * 32;
  float xv[32];
  float ss = 0.f;
#pragma unroll
  for (int i = 0; i < 4; ++i) {
    u16x8 cv = *(const u16x8*)(cp + i * 8);
    u16x8 zv = *(const u16x8*)(zp + i * 8);
#pragma unroll
    for (int e = 0; e < 8; ++e) {
      float z = b2f(zv[e]);
      float xx = b2f(cv[e]) * (z / (1.f + __expf(-z)));
      xv[i * 8 + e] = xx;
      ss = fmaf(xx, xx, ss);
    }
  }
  ss += dppmv<0xB1>(ss);
  ss += dppmv<0x4E>(ss);
  const float scl = rsqrtf(ss * (1.f / 128.f) + 1e-6f);
  u16* xo = x + (size_t)t * 4096 + hv * DKK + q * 32;
#pragma unroll
  for (int i = 0; i < 4; ++i) {
    u16x8 pk;
#pragma unroll
    for (int e = 0; e < 8; ++e) pk[e] = f2bf(xv[i * 8 + e] * scl * nw[q * 32 + i * 8 + e]);
    *(u16x8*)(xo + i * 8) = pk;
  }
}

extern "C" void kernel_launch(void* const* d_in, const int* in_sizes, int n_in,
                              void* d_out, int out_size, void* d_ws, size_t ws_size,
                              hipStream_t stream) {
  const float* h    = (const float*)d_in[0];
  const float* Wq   = (const float*)d_in[1];
  const float* Wk   = (const float*)d_in[2];
  const float* Wv   = (const float*)d_in[3];
  const float* Wz   = (const float*)d_in[4];
  const float* Wb   = (const float*)d_in[5];
  const float* Wa   = (const float*)d_in[6];
  const float* Alog = (const float*)d_in[7];
  const float* dtb  = (const float*)d_in[8];
  const float* nw   = (const float*)d_in[9];
  const float* Wo   = (const float*)d_in[10];
  char* ws = (char*)d_ws;
  // layout: [0..64M) UM_g (R1 out; earlier aliased by h_bf 0..16M + Wt 16..66.3M; later xbuf 16.8..50.3M)
  // [67.1M) Wto 16.8M | [83.9M) qkvz 100.7M | [184.5M) core 33.6M | [218.1M) beta/g/cumL
  u16* h_bf  = (u16*)(ws);
  u16* Wt    = (u16*)(ws + 16777216ull);
  u16* UM    = (u16*)(ws);                    // [2048][64][256] bf16 = 64MB (after GEMM)
  u16* Wto   = (u16*)(ws + 67108864ull);
  u16* qkvz  = (u16*)(ws + 83886080ull);
  u16* core  = (u16*)(ws + 184549376ull);     // [4096][4096] bf16 row-major
  u16* xbuf  = (u16*)(ws + 16777216ull);      // aliases UM tail (dead after R2)
  float* beta  = (float*)(ws + 218103808ull);
  float* g     = (float*)(ws + 218103808ull + 524288ull);
  float* cumL  = (float*)(ws + 218103808ull + 1048576ull);

  k_cvt<<<8192, 256, 0, stream>>>(h, h_bf, LTOK * DHID);
  k_tr<<<dim3(64, 64), 256, 0, stream>>>(Wq, Wt, 2048, 2048);
  k_tr<<<dim3(64, 64), 256, 0, stream>>>(Wk, Wt + 2048ull * 2048, 2048, 2048);
  k_tr<<<dim3(128, 64), 256, 0, stream>>>(Wv, Wt + 4096ull * 2048, 2048, 4096);
  k_tr<<<dim3(128, 64), 256, 0, stream>>>(Wz, Wt + 8192ull * 2048, 2048, 4096);
  k_tr<<<dim3(64, 128), 256, 0, stream>>>(Wo, Wto, 4096, 2048);
  k_gemm<u16><<<dim3(96, 32), 256, 0, stream>>>(h_bf, Wt, qkvz, 4096, 12288, 2048);
  k_ba<<<1024, 256, 0, stream>>>(h, Wb, Wa, Alog, dtb, beta, g);
  k_l2n<<<32768, 256, 0, stream>>>(qkvz);
  k_r1<<<2048, 256, 0, stream>>>(qkvz, beta, g, UM, cumL);
  k_r2<<<128, 256, 0, stream>>>(qkvz, UM, cumL, core);
  k_gnorm<<<dim3(64, 32), 256, 0, stream>>>(core, qkvz, nw, xbuf);
  k_gemm<float><<<dim3(16, 32), 256, 0, stream>>>(xbuf, Wto, (float*)d_out, 4096, 2048, 4096);
}